// Round 5
// baseline (350.344 us; speedup 1.0000x reference)
//
#include <hip/hip_runtime.h>
#include <hip/hip_fp16.h>
#include <cstdint>
#include <cstddef>

// Problem constants
#define NB 512
#define NR 1152
#define NC 8
#define NJ 10
#define NO 16
#define NJO 160   // NJ*NO

typedef unsigned int uint32;

union H2U { __half2 h; uint32 u; };

__device__ __forceinline__ uint32 packf16(float a0, float a1) {
    H2U p;
    p.h = __halves2half2(__float2half_rn(a0), __float2half_rn(a1));
    return p.u;
}
__device__ __forceinline__ float2 unpackf16(uint32 w) {
    H2U p; p.u = w;
    return __half22float2(p.h);
}

// ============================================================================
// Kernel 0: transpose x[b][r][c] -> xT[r][b][c]. (R1-exact: reverted; the
// R2/R3 "improvements" to the producer path were net-negative vs this.)
// ============================================================================
__global__ __launch_bounds__(256) void xpose_kernel(const float* __restrict__ x,
                                                    float* __restrict__ xT) {
    const int r0 = blockIdx.x * 16;
    const int b0 = blockIdx.y * 64;
    const int t  = threadIdx.x;
    __shared__ float tile[16][65][8];

    for (int i = t; i < 2048; i += 256) {
        int b = i >> 5, r = (i >> 1) & 15, h = i & 1;
        float4 v = *(const float4*)&x[(size_t)(b0 + b) * (NR * NC) + (size_t)(r0 + r) * NC + h * 4];
        *(float4*)&tile[r][b][h * 4] = v;
    }
    __syncthreads();
    for (int i = t; i < 2048; i += 256) {
        int r = i >> 7, b = (i >> 1) & 63, h = i & 1;
        float4 v = *(const float4*)&tile[r][b][h * 4];
        *(float4*)&xT[(size_t)(r0 + r) * (NB * NC) + (size_t)(b0 + b) * NC + h * 4] = v;
    }
}

// ============================================================================
// Kernel 1: u_hat -> f16 pairs in QUAD-BLOCKED row layout. (R1-exact.)
// ============================================================================
__global__ __launch_bounds__(320) void uhat_kernel(const float* __restrict__ xT,
                                                   const float* __restrict__ W,
                                                   uint32* __restrict__ u) {
    const int r = blockIdx.x;
    const int t = threadIdx.x;

    __shared__ float Ws[NC][NJO + 4];   // stride 164: staging conflict-free
    __shared__ float xs[NB][NC];

    for (int i = t; i < NJO * NC; i += 320) {
        Ws[i & 7][i >> 3] = W[(size_t)r * (NJO * NC) + i];
    }
    {
        const float4* xsrc = (const float4*)(xT + (size_t)r * (NB * NC));
        float4* xdst = (float4*)&xs[0][0];
        for (int i = t; i < (NB * NC) / 4; i += 320) xdst[i] = xsrc[i];
    }
    __syncthreads();

    const int ni   = t % 80;   // u32 slot in the permuted row
    const int half = t / 80;
    const int qt  = ni / 20;
    const int rem = ni % 20;
    const int j   = rem >> 1;
    const int d   = rem & 1;
    const int jo0 = 16 * j + 4 * qt + 2 * d;   // o index pair (jo0, jo0+1)

    float w0[8], w1[8];
#pragma unroll
    for (int c = 0; c < 8; ++c) {
        w0[c] = Ws[c][jo0];
        w1[c] = Ws[c][jo0 + 1];
    }

    for (int b = half; b < NB; b += 4) {
        const float4* xp = (const float4*)xs[b];
        float4 xa = xp[0], xb = xp[1];
        float a0 = w0[0] * xa.x + w0[1] * xa.y + w0[2] * xa.z + w0[3] * xa.w
                 + w0[4] * xb.x + w0[5] * xb.y + w0[6] * xb.z + w0[7] * xb.w;
        float a1 = w1[0] * xa.x + w1[1] * xa.y + w1[2] * xa.z + w1[3] * xa.w
                 + w1[4] * xb.x + w1[5] * xb.y + w1[6] * xb.z + w1[7] * xb.w;
        u[(size_t)(b * NR + r) * 80 + ni] = packf16(a0, a1);
    }
}

// ============================================================================
// Merged routing kernel, R4 change: register ping-pong on the row loads done
// WITHOUT any function boundary (R1's attempt passed arrays through a
// function => SROA failure => 327 MB scratch). Two row buffers are NAMED
// uint4 scalars; the body is a macro; local arrays (ur/cj/acc) are
// const-indexed only (R0-proven SROA-safe). Row c8+1's 5 dwordx4 issue
// before row c8 is consumed -> compiler emits partial vmcnt waits ->
// L2/L3 latency hides under ~400 cy of per-row compute. Work is only
// 18 waves/CU total (512 blocks x 9 waves), so TLP alone cannot hide
// latency; this supplies the missing ILP.
// ============================================================================
#define LOADROW(Q0, Q1, Q2, Q3, Q4, ROW)                                      \
    {                                                                         \
        const uint4* up_ = (const uint4*)(ubase + (size_t)(ROW) * 80);        \
        Q0 = up_[0]; Q1 = up_[1]; Q2 = up_[2]; Q3 = up_[3]; Q4 = up_[4];      \
    }

#define PROCESS(Q0, Q1, Q2, Q3, Q4)                                           \
    {                                                                         \
        uint32 ur[20];                                                        \
        ur[0] = Q0.x; ur[1] = Q0.y; ur[2] = Q0.z; ur[3] = Q0.w;               \
        ur[4] = Q1.x; ur[5] = Q1.y; ur[6] = Q1.z; ur[7] = Q1.w;               \
        ur[8] = Q2.x; ur[9] = Q2.y; ur[10] = Q2.z; ur[11] = Q2.w;             \
        ur[12] = Q3.x; ur[13] = Q3.y; ur[14] = Q3.z; ur[15] = Q3.w;           \
        ur[16] = Q4.x; ur[17] = Q4.y; ur[18] = Q4.z; ur[19] = Q4.w;           \
        float cj[NJ];                                                         \
        if (it == 0) {                                                        \
            _Pragma("unroll")                                                 \
            for (int j = 0; j < NJ; ++j) cj[j] = 0.1f;                        \
        } else {                                                              \
            float sum = 0.0f;                                                 \
            _Pragma("unroll")                                                 \
            for (int j = 0; j < NJ; ++j) {                                    \
                float2 ua = unpackf16(ur[2 * j]);                             \
                float2 ub = unpackf16(ur[2 * j + 1]);                         \
                float4 vv = *(const float4*)&vls[16 * j + 4 * qt];            \
                float pj = ua.x * vv.x + ua.y * vv.y + ub.x * vv.z + ub.y * vv.w; \
                pj += __shfl_xor(pj, 1);                                      \
                pj += __shfl_xor(pj, 2);                                      \
                float e = __expf(pj);                                         \
                cj[j] = e;                                                    \
                sum += e;                                                     \
            }                                                                 \
            float inv = 1.0f / sum;                                           \
            _Pragma("unroll")                                                 \
            for (int j = 0; j < NJ; ++j) cj[j] *= inv;                        \
        }                                                                     \
        _Pragma("unroll")                                                     \
        for (int j = 0; j < NJ; ++j) {                                        \
            float2 ua = unpackf16(ur[2 * j]);                                 \
            float2 ub = unpackf16(ur[2 * j + 1]);                             \
            acc[4 * j + 0] += cj[j] * ua.x;                                   \
            acc[4 * j + 1] += cj[j] * ua.y;                                   \
            acc[4 * j + 2] += cj[j] * ub.x;                                   \
            acc[4 * j + 3] += cj[j] * ub.y;                                   \
        }                                                                     \
    }

__global__ __launch_bounds__(576, 2) void routing_kernel(const uint32* __restrict__ u,
                                                         float* __restrict__ outp) {
    const int b  = blockIdx.x;
    const int t  = threadIdx.x;
    const int w  = t >> 6;        // wave 0..8
    const int l  = t & 63;
    const int m  = (l >> 2) & 15; // row within chunk
    const int qt = l & 3;         // o-quarter

    __shared__ float sl[NJO];     // s accumulator
    __shared__ float vls[NJO];    // current v-sum (fp32), read by dot
    __shared__ float vaccl[NJO];  // running v0+v1 (fp32)

    for (int i = t; i < NJO; i += 576) sl[i] = 0.0f;
    __syncthreads();

    const uint32* ubase = u + (size_t)b * (NR * 80) + qt * 20;
    const int rbase = w * 8 * 16 + m;   // row(c8) = rbase + c8*16

#pragma unroll 1
    for (int it = 0; it < 3; ++it) {
        float acc[40];
#pragma unroll
        for (int i = 0; i < 40; ++i) acc[i] = 0.0f;

        uint4 qa0, qa1, qa2, qa3, qa4;
        uint4 qb0, qb1, qb2, qb3, qb4;

        LOADROW(qa0, qa1, qa2, qa3, qa4, rbase)

#pragma unroll 1
        for (int c8 = 0; c8 < 8; c8 += 2) {
            LOADROW(qb0, qb1, qb2, qb3, qb4, rbase + (c8 + 1) * 16)
            PROCESS(qa0, qa1, qa2, qa3, qa4)
            if (c8 < 6) {
                LOADROW(qa0, qa1, qa2, qa3, qa4, rbase + (c8 + 2) * 16)
            }
            PROCESS(qb0, qb1, qb2, qb3, qb4)
        }

        // ---- reduce-scatter among the 16 same-qt lanes (masks 4,8,16,32) ----
        float a[24];
        {
            const int bit = (l >> 2) & 1;
#pragma unroll
            for (int i = 0; i < 24; ++i) {
                float lo = acc[i];
                float hi = (i + 24 < 40) ? acc[i + 24] : 0.0f;
                float send = bit ? lo : hi;
                float recv = __shfl_xor(send, 4);
                a[i] = (bit ? hi : lo) + recv;
            }
        }
#pragma unroll
        for (int st = 1; st < 4; ++st) {
            const int h = 24 >> st;              // 12,6,3
            const int bit = (l >> (2 + st)) & 1;
#pragma unroll
            for (int i = 0; i < 12; ++i) {
                if (i < h) {
                    float send = bit ? a[i] : a[i + h];
                    float recv = __shfl_xor(send, 4 << st);
                    a[i] = (bit ? a[i + h] : a[i]) + recv;
                }
            }
        }
        const int base = 3 * (__brev((uint32)m) >> 28);
#pragma unroll
        for (int i = 0; i < 3; ++i) {
            int aidx = base + i;
            if (aidx < 40) {
                int j = aidx >> 2, e = aidx & 3;
                atomicAdd(&sl[16 * j + 4 * qt + e], a[i]);
            }
        }
        __syncthreads();

        // ---- in-block squash: thread p<80 owns o-pair (2p, 2p+1) ----
        if (t < 80) {
            float2 sv = *(const float2*)&sl[2 * t];
            float sq = sv.x * sv.x + sv.y * sv.y;
#pragma unroll
            for (int off = 1; off < 8; off <<= 1) sq += __shfl_xor(sq, off, 8);
            float scale = (sq / (1.0f + sq)) * rsqrtf(sq + 1e-8f);
            float vx = sv.x * scale, vy = sv.y * scale;
            if (it == 2) {
                *(float2*)&outp[b * NJO + 2 * t] = make_float2(vx, vy);
            } else {
                float2 va;
                if (it == 0) va = make_float2(vx, vy);
                else {
                    va = *(const float2*)&vaccl[2 * t];
                    va.x += vx; va.y += vy;
                }
                *(float2*)&vaccl[2 * t] = va;
                *(float2*)&vls[2 * t]   = va;
            }
        }
        __syncthreads();
        if (it < 2) {
            for (int i = t; i < NJO; i += 576) sl[i] = 0.0f;
            __syncthreads();
        }
    }
}

// ============================================================================
extern "C" void kernel_launch(void* const* d_in, const int* in_sizes, int n_in,
                              void* d_out, int out_size, void* d_ws, size_t ws_size,
                              hipStream_t stream) {
    (void)in_sizes; (void)n_in; (void)out_size; (void)ws_size;

    const float* x = (const float*)d_in[0];  // [B,R,C]
    const float* W = (const float*)d_in[1];  // [R,J,O,C]
    float* out = (float*)d_out;              // [B,J,O,1] fp32

    char* ws = (char*)d_ws;
    const size_t XBYTES = (size_t)NR * NB * NC * 4;   // 18,874,368
    float*  xT = (float*)ws;
    uint32* u  = (uint32*)(ws + XBYTES);              // [B,R,80] f16 pairs

    xpose_kernel<<<dim3(NR / 16, NB / 64), 256, 0, stream>>>(x, xT);
    uhat_kernel<<<NR, 320, 0, stream>>>(xT, W, u);
    routing_kernel<<<NB, 576, 0, stream>>>(u, out);
}

// Round 6
// 210.898 us; speedup vs baseline: 1.6612x; 1.6612x over previous
//
#include <hip/hip_runtime.h>
#include <hip/hip_fp16.h>
#include <cstdint>
#include <cstddef>

// Problem constants
#define NB 512
#define NR 1152
#define NC 8
#define NJ 10
#define NO 16
#define NJO 160   // NJ*NO

typedef unsigned int uint32;

union H2U { __half2 h; uint32 u; };

__device__ __forceinline__ uint32 packf16(float a0, float a1) {
    H2U p;
    p.h = __halves2half2(__float2half_rn(a0), __float2half_rn(a1));
    return p.u;
}
__device__ __forceinline__ float2 unpackf16(uint32 w) {
    H2U p; p.u = w;
    return __half22float2(p.h);
}

// ============================================================================
// Kernel 0: transpose x[b][r][c] -> xT[r][b][c]. (R1-exact.)
// ============================================================================
__global__ __launch_bounds__(256) void xpose_kernel(const float* __restrict__ x,
                                                    float* __restrict__ xT) {
    const int r0 = blockIdx.x * 16;
    const int b0 = blockIdx.y * 64;
    const int t  = threadIdx.x;
    __shared__ float tile[16][65][8];

    for (int i = t; i < 2048; i += 256) {
        int b = i >> 5, r = (i >> 1) & 15, h = i & 1;
        float4 v = *(const float4*)&x[(size_t)(b0 + b) * (NR * NC) + (size_t)(r0 + r) * NC + h * 4];
        *(float4*)&tile[r][b][h * 4] = v;
    }
    __syncthreads();
    for (int i = t; i < 2048; i += 256) {
        int r = i >> 7, b = (i >> 1) & 63, h = i & 1;
        float4 v = *(const float4*)&tile[r][b][h * 4];
        *(float4*)&xT[(size_t)(r0 + r) * (NB * NC) + (size_t)(b0 + b) * NC + h * 4] = v;
    }
}

// ============================================================================
// Kernel 1: u_hat -> f16 pairs. R5 layout: OCTO-GROUPED rows.
// Row (b,r) = 80 u32; slot ni = g*10 + 2*jloc + d, where g = qt*2 + jh,
// j = jh*5 + jloc, holds f16 pair (o = 4qt+2d, 4qt+2d+1) of capsule j.
// A routing lane owning (qt,jh) reads u32s [g*10, g*10+10) -- contiguous,
// 5 x dwordx2 (8B-aligned: g*40 bytes). Structure otherwise R1-exact.
// ============================================================================
__global__ __launch_bounds__(320) void uhat_kernel(const float* __restrict__ xT,
                                                   const float* __restrict__ W,
                                                   uint32* __restrict__ u) {
    const int r = blockIdx.x;
    const int t = threadIdx.x;

    __shared__ float Ws[NC][NJO + 4];   // stride 164: staging conflict-free
    __shared__ float xs[NB][NC];

    for (int i = t; i < NJO * NC; i += 320) {
        Ws[i & 7][i >> 3] = W[(size_t)r * (NJO * NC) + i];
    }
    {
        const float4* xsrc = (const float4*)(xT + (size_t)r * (NB * NC));
        float4* xdst = (float4*)&xs[0][0];
        for (int i = t; i < (NB * NC) / 4; i += 320) xdst[i] = xsrc[i];
    }
    __syncthreads();

    const int ni   = t % 80;   // u32 slot in the permuted row
    const int half = t / 80;
    const int g    = ni / 10;        // (qt,jh) group
    const int rem  = ni % 10;
    const int qt   = g >> 1;
    const int jh   = g & 1;
    const int j    = jh * 5 + (rem >> 1);
    const int d    = rem & 1;
    const int jo0  = 16 * j + 4 * qt + 2 * d;   // o index pair (jo0, jo0+1)

    float w0[8], w1[8];
#pragma unroll
    for (int c = 0; c < 8; ++c) {
        w0[c] = Ws[c][jo0];
        w1[c] = Ws[c][jo0 + 1];
    }

    for (int b = half; b < NB; b += 4) {
        const float4* xp = (const float4*)xs[b];
        float4 xa = xp[0], xb = xp[1];
        float a0 = w0[0] * xa.x + w0[1] * xa.y + w0[2] * xa.z + w0[3] * xa.w
                 + w0[4] * xb.x + w0[5] * xb.y + w0[6] * xb.z + w0[7] * xb.w;
        float a1 = w1[0] * xa.x + w1[1] * xa.y + w1[2] * xa.z + w1[3] * xa.w
                 + w1[4] * xb.x + w1[5] * xb.y + w1[6] * xb.z + w1[7] * xb.w;
        u[(size_t)(b * NR + r) * 80 + ni] = packf16(a0, a1);
    }
}

// ============================================================================
// Merged routing kernel. R5 decomposition: 8 lanes per row (qt = l&3 o-quarter,
// jh = (l>>2)&1 capsule-half, mloc = l>>3 row-in-group). Halves per-lane
// state (acc[20], 10 u32/row, cj[5]) so a 1-row-deep register ping-pong fits
// the ~84-VGPR cap that killed R1/R4 (both spilled acc -> 280+ MB scratch).
// Ping-pong: row c16+1's 5 dwordx2 issue before row c16 is consumed ->
// partial vmcnt waits -> L2/L3 latency hides under ~80 inst of row compute.
// Softmax: 5 local dots + xor1/xor2 (o-combine) + xor4 (jh denominator).
// Reduce-scatter: 3 stages (masks 8/16/32) over 24-padded acc, brev scatter,
// <=3 LDS atomics/lane (proven R0 scheme, resized).
// ============================================================================
#define LOADROW(Q0, Q1, Q2, Q3, Q4, ROW)                                      \
    {                                                                         \
        const uint32* p_ = ubase + (size_t)(ROW) * 80;                        \
        Q0 = *(const uint2*)(p_);     Q1 = *(const uint2*)(p_ + 2);           \
        Q2 = *(const uint2*)(p_ + 4); Q3 = *(const uint2*)(p_ + 6);           \
        Q4 = *(const uint2*)(p_ + 8);                                         \
    }

#define PROCESS(Q0, Q1, Q2, Q3, Q4)                                           \
    {                                                                         \
        uint32 ur[10];                                                        \
        ur[0] = Q0.x; ur[1] = Q0.y; ur[2] = Q1.x; ur[3] = Q1.y;               \
        ur[4] = Q2.x; ur[5] = Q2.y; ur[6] = Q3.x; ur[7] = Q3.y;               \
        ur[8] = Q4.x; ur[9] = Q4.y;                                           \
        float cj[5];                                                          \
        if (it == 0) {                                                        \
            _Pragma("unroll")                                                 \
            for (int jl = 0; jl < 5; ++jl) cj[jl] = 0.1f;                     \
        } else {                                                              \
            float sum = 0.0f;                                                 \
            _Pragma("unroll")                                                 \
            for (int jl = 0; jl < 5; ++jl) {                                  \
                float2 ua = unpackf16(ur[2 * jl]);                            \
                float2 ub = unpackf16(ur[2 * jl + 1]);                        \
                float4 vv = *(const float4*)&vls[vbase + 16 * jl];            \
                float pj = ua.x * vv.x + ua.y * vv.y + ub.x * vv.z + ub.y * vv.w; \
                pj += __shfl_xor(pj, 1);                                      \
                pj += __shfl_xor(pj, 2);                                      \
                float e = __expf(pj);                                         \
                cj[jl] = e;                                                   \
                sum += e;                                                     \
            }                                                                 \
            sum += __shfl_xor(sum, 4);                                        \
            float inv = 1.0f / sum;                                           \
            _Pragma("unroll")                                                 \
            for (int jl = 0; jl < 5; ++jl) cj[jl] *= inv;                     \
        }                                                                     \
        _Pragma("unroll")                                                     \
        for (int jl = 0; jl < 5; ++jl) {                                      \
            float2 ua = unpackf16(ur[2 * jl]);                                \
            float2 ub = unpackf16(ur[2 * jl + 1]);                            \
            acc[4 * jl + 0] += cj[jl] * ua.x;                                 \
            acc[4 * jl + 1] += cj[jl] * ua.y;                                 \
            acc[4 * jl + 2] += cj[jl] * ub.x;                                 \
            acc[4 * jl + 3] += cj[jl] * ub.y;                                 \
        }                                                                     \
    }

__global__ __launch_bounds__(576, 2) void routing_kernel(const uint32* __restrict__ u,
                                                         float* __restrict__ outp) {
    const int b    = blockIdx.x;
    const int t    = threadIdx.x;
    const int w    = t >> 6;          // wave 0..8
    const int l    = t & 63;
    const int qt   = l & 3;           // o-quarter
    const int jh   = (l >> 2) & 1;    // capsule half
    const int mloc = l >> 3;          // row within 8-group
    const int g    = qt * 2 + jh;     // u32-group in row

    __shared__ float sl[NJO];     // s accumulator
    __shared__ float vls[NJO];    // current v-sum (fp32), read by dot
    __shared__ float vaccl[NJO];  // running v0+v1 (fp32)

    for (int i = t; i < NJO; i += 576) sl[i] = 0.0f;
    __syncthreads();

    const uint32* ubase = u + (size_t)b * (NR * 80) + g * 10;
    const int vbase = jh * 80 + qt * 4;     // vls[16*(jh*5+jl) + 4*qt]
    const int rbase = w * 128 + mloc;       // row(c16) = rbase + c16*8

#pragma unroll 1
    for (int it = 0; it < 3; ++it) {
        float acc[20];
#pragma unroll
        for (int i = 0; i < 20; ++i) acc[i] = 0.0f;

        uint2 qa0, qa1, qa2, qa3, qa4;
        uint2 qb0, qb1, qb2, qb3, qb4;

        LOADROW(qa0, qa1, qa2, qa3, qa4, rbase)

#pragma unroll 1
        for (int c16 = 0; c16 < 16; c16 += 2) {
            LOADROW(qb0, qb1, qb2, qb3, qb4, rbase + (c16 + 1) * 8)
            PROCESS(qa0, qa1, qa2, qa3, qa4)
            if (c16 < 14) {
                LOADROW(qa0, qa1, qa2, qa3, qa4, rbase + (c16 + 2) * 8)
            }
            PROCESS(qb0, qb1, qb2, qb3, qb4)
        }

        // ---- reduce-scatter among the 8 same-(qt,jh) lanes (masks 8,16,32) ----
        float a[12];
        {
            const int bit = (l >> 3) & 1;
#pragma unroll
            for (int i = 0; i < 12; ++i) {
                float lo = acc[i];
                float hi = (i + 12 < 20) ? acc[i + 12] : 0.0f;
                float send = bit ? lo : hi;
                float recv = __shfl_xor(send, 8);
                a[i] = (bit ? hi : lo) + recv;
            }
        }
#pragma unroll
        for (int st = 1; st < 3; ++st) {
            const int h = 12 >> st;              // 6,3
            const int bit = (l >> (3 + st)) & 1;
#pragma unroll
            for (int i = 0; i < 6; ++i) {
                if (i < h) {
                    float send = bit ? a[i] : a[i + h];
                    float recv = __shfl_xor(send, 8 << st);
                    a[i] = (bit ? a[i + h] : a[i]) + recv;
                }
            }
        }
        const int base = 3 * (__brev((uint32)mloc) >> 29);
#pragma unroll
        for (int i = 0; i < 3; ++i) {
            int aidx = base + i;
            if (aidx < 20) {
                int jl = aidx >> 2, e = aidx & 3;
                atomicAdd(&sl[16 * (jh * 5 + jl) + 4 * qt + e], a[i]);
            }
        }
        __syncthreads();

        // ---- in-block squash: thread p<80 owns o-pair (2p, 2p+1) ----
        if (t < 80) {
            float2 sv = *(const float2*)&sl[2 * t];
            float sq = sv.x * sv.x + sv.y * sv.y;
#pragma unroll
            for (int off = 1; off < 8; off <<= 1) sq += __shfl_xor(sq, off, 8);
            float scale = (sq / (1.0f + sq)) * rsqrtf(sq + 1e-8f);
            float vx = sv.x * scale, vy = sv.y * scale;
            if (it == 2) {
                *(float2*)&outp[b * NJO + 2 * t] = make_float2(vx, vy);
            } else {
                float2 va;
                if (it == 0) va = make_float2(vx, vy);
                else {
                    va = *(const float2*)&vaccl[2 * t];
                    va.x += vx; va.y += vy;
                }
                *(float2*)&vaccl[2 * t] = va;
                *(float2*)&vls[2 * t]   = va;
            }
        }
        __syncthreads();
        if (it < 2) {
            for (int i = t; i < NJO; i += 576) sl[i] = 0.0f;
            __syncthreads();
        }
    }
}

// ============================================================================
extern "C" void kernel_launch(void* const* d_in, const int* in_sizes, int n_in,
                              void* d_out, int out_size, void* d_ws, size_t ws_size,
                              hipStream_t stream) {
    (void)in_sizes; (void)n_in; (void)out_size; (void)ws_size;

    const float* x = (const float*)d_in[0];  // [B,R,C]
    const float* W = (const float*)d_in[1];  // [R,J,O,C]
    float* out = (float*)d_out;              // [B,J,O,1] fp32

    char* ws = (char*)d_ws;
    const size_t XBYTES = (size_t)NR * NB * NC * 4;   // 18,874,368
    float*  xT = (float*)ws;
    uint32* u  = (uint32*)(ws + XBYTES);              // [B,R,80] f16 pairs

    xpose_kernel<<<dim3(NR / 16, NB / 64), 256, 0, stream>>>(x, xT);
    uhat_kernel<<<NR, 320, 0, stream>>>(xT, W, u);
    routing_kernel<<<NB, 576, 0, stream>>>(u, out);
}